// Round 6
// baseline (171.539 us; speedup 1.0000x reference)
//
#include <hip/hip_runtime.h>

constexpr int NB = 2;
constexpr int NC = 64;
constexpr int NH = 192;
constexpr int NW = 192;
constexpr int NK = 7;
constexpr int NHW = NH * NW;          // 36864
constexpr int NPIX = NB * NHW;        // 73728
constexpr float EPS = 1e-6f;

// ---------------------------------------------------------------------------
// Kernel 1: layernorm + 1x1 conv as LDS-tiled GEMM.  (unchanged from R3/R4)
// ---------------------------------------------------------------------------
__global__ __launch_bounds__(256) void qk_gemm(
    const float* __restrict__ g, const float* __restrict__ cd,
    const float* __restrict__ mask,
    const float* __restrict__ ln_w, const float* __restrict__ ln_b,
    const float* __restrict__ conv_w, const float* __restrict__ conv_b,
    float* __restrict__ qbuf, float* __restrict__ kbuf)
{
    __shared__ float Z[65][128];
    __shared__ float WTc[33][128];

    int tid = threadIdx.x;
    int p0 = blockIdx.x * 128;
    int b  = p0 / NHW;
    int hw0 = p0 - b * NHW;

    int px = tid >> 1;
    int hf = tid & 1;
    const float* gp = g + (size_t)(b * NC + hf * 32) * NHW + (hw0 + px);
    float vals[32];
    float s = 0.f, sq = 0.f;
#pragma unroll
    for (int j = 0; j < 32; ++j) {
        float v = gp[(size_t)j * NHW];
        vals[j] = v; s += v; sq += v * v;
    }
    s  += __shfl_xor(s, 1);
    sq += __shfl_xor(sq, 1);
    float mu   = s * (1.f / 64.f);
    float rstd = rsqrtf(sq * (1.f / 64.f) - mu * mu + EPS);
#pragma unroll
    for (int j = 0; j < 32; ++j) {
        int c = hf * 32 + j;
        Z[c][px] = (vals[j] - mu) * rstd * ln_w[c] + ln_b[c];
    }
    if (hf) Z[64][px] = cd[p0 + px];

    int og = tid >> 4;
    int pg = tid & 15;
    float acc[8][8];
#pragma unroll
    for (int oi = 0; oi < 8; ++oi)
#pragma unroll
        for (int pj = 0; pj < 8; ++pj) acc[oi][pj] = 0.f;

    for (int cc = 0; cc < 65; cc += 33) {
        int nr = (65 - cc < 33) ? (65 - cc) : 33;
        __syncthreads();
        if (tid < 128) {
            int o = tid;
            for (int r = 0; r < nr; ++r)
                WTc[r][o] = conv_w[o * 65 + cc + r];
        }
        __syncthreads();
        for (int r = 0; r < nr; ++r) {
            float4 w0 = *(const float4*)&WTc[r][8 * og];
            float4 w1 = *(const float4*)&WTc[r][8 * og + 4];
            float4 z0 = *(const float4*)&Z[cc + r][8 * pg];
            float4 z1 = *(const float4*)&Z[cc + r][8 * pg + 4];
            float w8[8] = {w0.x, w0.y, w0.z, w0.w, w1.x, w1.y, w1.z, w1.w};
            float z8[8] = {z0.x, z0.y, z0.z, z0.w, z1.x, z1.y, z1.z, z1.w};
#pragma unroll
            for (int oi = 0; oi < 8; ++oi)
#pragma unroll
                for (int pj = 0; pj < 8; ++pj)
                    acc[oi][pj] = fmaf(w8[oi], z8[pj], acc[oi][pj]);
        }
    }

    int o0  = og * 8;
    int pxb = pg * 8;
    float4 ba = *(const float4*)&conv_b[o0];
    float4 bb = *(const float4*)&conv_b[o0 + 4];
    float bia[8] = {ba.x, ba.y, ba.z, ba.w, bb.x, bb.y, bb.z, bb.w};
    bool isq = (o0 < 64);
    float m8[8];
    if (!isq) {
        float4 ma = *(const float4*)&mask[p0 + pxb];
        float4 mc = *(const float4*)&mask[p0 + pxb + 4];
        m8[0]=ma.x; m8[1]=ma.y; m8[2]=ma.z; m8[3]=ma.w;
        m8[4]=mc.x; m8[5]=mc.y; m8[6]=mc.z; m8[7]=mc.w;
    }
    float* base = isq ? (qbuf + (size_t)(b * NC + o0) * NHW + hw0 + pxb)
                      : (kbuf + (size_t)(b * NC + o0 - 64) * NHW + hw0 + pxb);
#pragma unroll
    for (int oi = 0; oi < 8; ++oi) {
        float v[8];
#pragma unroll
        for (int pj = 0; pj < 8; ++pj) {
            float t = acc[oi][pj] + bia[oi];
            v[pj] = isq ? t : t * m8[pj];
        }
        float* dst = base + (size_t)oi * NHW;
        *(float4*)&dst[0] = make_float4(v[0], v[1], v[2], v[3]);
        *(float4*)&dst[4] = make_float4(v[4], v[5], v[6], v[7]);
    }
}

// ---------------------------------------------------------------------------
// Kernel 2 (v6): DPP-shift windowed attention. Wave = 64-lane row strip:
// 48 active px + 8 halo lanes each side (192 = 4 strips x 48).
// DPP direction facts (GCN/CDNA ISA): wave_shr:1 (0x138) => lane i <- i-1;
//                                     wave_shl:1 (0x130) => lane i <- i+1.
// (R5 had these swapped -> mirrored windows, absmax 0.35.)
// ---------------------------------------------------------------------------
__device__ inline float dpp_p1(float x) {   // lane i <- lane i+1 (wave_shl:1)
    return __int_as_float(__builtin_amdgcn_mov_dpp(
        __float_as_int(x), 0x130, 0xf, 0xf, true));
}
__device__ inline float dpp_m1(float x) {   // lane i <- lane i-1 (wave_shr:1)
    return __int_as_float(__builtin_amdgcn_mov_dpp(
        __float_as_int(x), 0x138, 0xf, 0xf, true));
}

// MODE: 0 interior strip, 1 left-edge strip (s==0), 2 right-edge (s==3)
template <int MODE>
__device__ void attn_wave(
    int b, int h, int s, int lane,
    const float* __restrict__ qbuf, const float* __restrict__ kbuf,
    const float* __restrict__ cd, const float* __restrict__ sd,
    const float* __restrict__ mask, const float* __restrict__ rpb,
    float* __restrict__ out_cd, float* __restrict__ out_mask)
{
    int w0 = s * 48;
    int wp = w0 + lane - 8;                   // strip px col (halo: <0 / >191)
    int wc = min(max(wp, 0), NW - 1);         // clamped load col
    int rs = min(max(h - 3, 0), NH - NK);     // window top row (wave-uniform)
    int pr = 6 - (h - rs);                    // rpb row base (wave-uniform)

    const float* kb = kbuf + (size_t)b * NC * NHW;
    const float* qb = qbuf + (size_t)b * NC * NHW + h * NW + wc;

    float at[49];
#pragma unroll
    for (int n = 0; n < 49; ++n) at[n] = 0.f;
    float ax[21];                              // extended deltas (edge strips)
    if (MODE != 0) {
#pragma unroll
        for (int n = 0; n < 21; ++n) ax[n] = 0.f;
    }

    // q ring prefetch (4 deep), k rows double-buffered (1 channel ahead)
    float q0 = qb[0];
    float q1 = qb[(size_t)1 * NHW];
    float q2 = qb[(size_t)2 * NHW];
    float q3 = qb[(size_t)3 * NHW];
    float kvA[7], kvB[7];
#pragma unroll
    for (int r = 0; r < 7; ++r) kvA[r] = kb[(rs + r) * NW + wc];

    auto loadrow = [&](float (&dst)[7], int c) {
        const float* p = kb + (size_t)c * NHW;
#pragma unroll
        for (int r = 0; r < 7; ++r) dst[r] = p[(rs + r) * NW + wc];
    };
    auto compute = [&](float (&cur)[7], float qc) {
#pragma unroll
        for (int r = 0; r < 7; ++r) {
            float t0 = cur[r];
            float p1 = dpp_p1(t0), p2 = dpp_p1(p1), p3 = dpp_p1(p2);
            float m1 = dpp_m1(t0), m2 = dpp_m1(m1), m3 = dpp_m1(m2);
            at[r*7+0] = fmaf(qc, m3, at[r*7+0]);
            at[r*7+1] = fmaf(qc, m2, at[r*7+1]);
            at[r*7+2] = fmaf(qc, m1, at[r*7+2]);
            at[r*7+3] = fmaf(qc, t0, at[r*7+3]);
            at[r*7+4] = fmaf(qc, p1, at[r*7+4]);
            at[r*7+5] = fmaf(qc, p2, at[r*7+5]);
            at[r*7+6] = fmaf(qc, p3, at[r*7+6]);
            if (MODE == 1) {                   // deltas +4..+6
                float p4 = dpp_p1(p3), p5 = dpp_p1(p4), p6 = dpp_p1(p5);
                ax[r*3+0] = fmaf(qc, p4, ax[r*3+0]);
                ax[r*3+1] = fmaf(qc, p5, ax[r*3+1]);
                ax[r*3+2] = fmaf(qc, p6, ax[r*3+2]);
            }
            if (MODE == 2) {                   // deltas -4..-6
                float m4 = dpp_m1(m3), m5 = dpp_m1(m4), m6 = dpp_m1(m5);
                ax[r*3+0] = fmaf(qc, m4, ax[r*3+0]);
                ax[r*3+1] = fmaf(qc, m5, ax[r*3+1]);
                ax[r*3+2] = fmaf(qc, m6, ax[r*3+2]);
            }
        }
    };

    for (int c = 0; c < 64; c += 4) {
        if (c + 1 < 64) loadrow(kvB, c + 1);
        compute(kvA, q0);
        if (c + 4 < 64) q0 = qb[(size_t)(c + 4) * NHW];
        if (c + 2 < 64) loadrow(kvA, c + 2);
        compute(kvB, q1);
        if (c + 5 < 64) q1 = qb[(size_t)(c + 5) * NHW];
        if (c + 3 < 64) loadrow(kvB, c + 3);
        compute(kvA, q2);
        if (c + 6 < 64) q2 = qb[(size_t)(c + 6) * NHW];
        if (c + 4 < 64) loadrow(kvA, c + 4);
        compute(kvB, q3);
        if (c + 7 < 64) q3 = qb[(size_t)(c + 7) * NHW];
    }

    // ---- one-time remap from relative deltas to clipped-window (i,j) ----
    int cs = min(max(wp - 3, 0), NW - NK);
    int e  = cs - (wp - 3);                    // 0 interior; 1..3 L; -1..-3 R
    if (MODE == 1) {
#pragma unroll
        for (int i = 0; i < 7; ++i)
#pragma unroll
            for (int j = 0; j < 7; ++j) {      // ascending j: reads j+1..j+3
                float v = at[i*7+j];
                v = (e >= 1) ? ((j+1 <= 6) ? at[i*7+j+1] : ax[i*3+j-6]) : v;
                v = (e >= 2) ? ((j+2 <= 6) ? at[i*7+j+2] : ax[i*3+j-5]) : v;
                v = (e >= 3) ? ((j+3 <= 6) ? at[i*7+j+3] : ax[i*3+j-4]) : v;
                at[i*7+j] = v;
            }
    }
    if (MODE == 2) {
#pragma unroll
        for (int i = 0; i < 7; ++i)
#pragma unroll
            for (int jj = 6; jj >= 0; --jj) {  // descending j: reads j-1..j-3
                int j = jj;
                float v = at[i*7+j];
                v = (e <= -1) ? ((j >= 1) ? at[i*7+j-1] : ax[i*3+0]) : v;
                v = (e <= -2) ? ((j >= 2) ? at[i*7+j-2] : ax[i*3+1-j]) : v;
                v = (e <= -3) ? ((j >= 3) ? at[i*7+j-3] : ax[i*3+2-j]) : v;
                at[i*7+j] = v;
            }
    }

    // ---- relative-position bias (tiny, L2-resident) ----
    int pc = 3 + e;
    const float* rp = rpb + pr * 13 + pc;
#pragma unroll
    for (int i = 0; i < 7; ++i)
#pragma unroll
        for (int j = 0; j < 7; ++j)
            at[i*7+j] += rp[i * 13 + j];

    // ---- softmax over 49 ----
    float mx = -1e30f;
#pragma unroll
    for (int n = 0; n < 49; ++n) mx = fmaxf(mx, at[n]);
    float sm = 0.f;
#pragma unroll
    for (int n = 0; n < 49; ++n) { at[n] = __expf(at[n] - mx); sm += at[n]; }
    float inv = 1.f / sm;

    // ---- aggregate cd & mask windows via the same shift machinery ----
    const float* cdb = cd   + (size_t)b * NHW;
    const float* msb = mask + (size_t)b * NHW;
    float oc = 0.f, om = 0.f;
#pragma unroll
    for (int r = 0; r < 7; ++r) {
        float c0 = cdb[(rs + r) * NW + wc];
        float m0 = msb[(rs + r) * NW + wc];
        float cp1 = dpp_p1(c0), cp2 = dpp_p1(cp1), cp3 = dpp_p1(cp2);
        float cm1 = dpp_m1(c0), cm2 = dpp_m1(cm1), cm3 = dpp_m1(cm2);
        float mp1 = dpp_p1(m0), mp2 = dpp_p1(mp1), mp3 = dpp_p1(mp2);
        float mm1 = dpp_m1(m0), mm2 = dpp_m1(mm1), mm3 = dpp_m1(mm2);
        float cw[7] = {cm3, cm2, cm1, c0, cp1, cp2, cp3};
        float mw[7] = {mm3, mm2, mm1, m0, mp1, mp2, mp3};
        if (MODE == 1) {
            float cp4 = dpp_p1(cp3), cp5 = dpp_p1(cp4), cp6 = dpp_p1(cp5);
            float mp4 = dpp_p1(mp3), mp5 = dpp_p1(mp4), mp6 = dpp_p1(mp5);
            float cx[10] = {cm3,cm2,cm1,c0,cp1,cp2,cp3,cp4,cp5,cp6};
            float mxw[10] = {mm3,mm2,mm1,m0,mp1,mp2,mp3,mp4,mp5,mp6};
#pragma unroll
            for (int j = 0; j < 7; ++j) {
                float v = cx[j], u = mxw[j];
                v = (e >= 1) ? cx[j+1] : v;  u = (e >= 1) ? mxw[j+1] : u;
                v = (e >= 2) ? cx[j+2] : v;  u = (e >= 2) ? mxw[j+2] : u;
                v = (e >= 3) ? cx[j+3] : v;  u = (e >= 3) ? mxw[j+3] : u;
                cw[j] = v; mw[j] = u;
            }
        }
        if (MODE == 2) {
            float cm4 = dpp_m1(cm3), cm5 = dpp_m1(cm4), cm6 = dpp_m1(cm5);
            float mm4 = dpp_m1(mm3), mm5 = dpp_m1(mm4), mm6 = dpp_m1(mm5);
            float cx[10] = {cm6,cm5,cm4,cm3,cm2,cm1,c0,cp1,cp2,cp3};
            float mxw[10] = {mm6,mm5,mm4,mm3,mm2,mm1,m0,mp1,mp2,mp3};
            // cx[d+6] holds delta d (d = j-3+e ranges -6..3)
#pragma unroll
            for (int j = 0; j < 7; ++j) {
                float v = cx[j+3], u = mxw[j+3];
                v = (e <= -1) ? cx[j+2] : v;  u = (e <= -1) ? mxw[j+2] : u;
                v = (e <= -2) ? cx[j+1] : v;  u = (e <= -2) ? mxw[j+1] : u;
                v = (e <= -3) ? cx[j+0] : v;  u = (e <= -3) ? mxw[j+0] : u;
                cw[j] = v; mw[j] = u;
            }
        }
#pragma unroll
        for (int j = 0; j < 7; ++j) {
            oc = fmaf(at[r*7+j], cw[j], oc);
            om = fmaf(at[r*7+j], mw[j], om);
        }
    }
    oc *= inv; om *= inv;

    // ---- blend + sparse-depth override + store (active lanes only) ----
    float cdc = cdb[h * NW + wc];
    float mc  = msb[h * NW + wc];
    float sdc = sd[(size_t)b * NHW + h * NW + wc];
    float co = oc * mc + cdc * (1.f - mc);
    float mo = om;
    if (sdc > 0.f) { co = sdc; mo = mc; }
    if (lane >= 8 && lane < 56) {
        int p = b * NHW + h * NW + wp;
        out_cd[p] = co;
        out_mask[p] = mo;
    }
}

__global__ __launch_bounds__(256) void attn_dpp(
    const float* __restrict__ qbuf, const float* __restrict__ kbuf,
    const float* __restrict__ cd, const float* __restrict__ sd,
    const float* __restrict__ mask, const float* __restrict__ rpb,
    float* __restrict__ out_cd, float* __restrict__ out_mask)
{
    int tid  = threadIdx.x;
    int lane = tid & 63;
    int wave = tid >> 6;
    // block = 4 consecutive rows of one strip (k-row L1/L2 reuse)
    int blk = blockIdx.x;
    int b   = blk / 192;
    int r2  = blk % 192;
    int s   = r2 / 48;
    int h   = (r2 % 48) * 4 + wave;

    if (s == 0)
        attn_wave<1>(b, h, s, lane, qbuf, kbuf, cd, sd, mask, rpb, out_cd, out_mask);
    else if (s == 3)
        attn_wave<2>(b, h, s, lane, qbuf, kbuf, cd, sd, mask, rpb, out_cd, out_mask);
    else
        attn_wave<0>(b, h, s, lane, qbuf, kbuf, cd, sd, mask, rpb, out_cd, out_mask);
}

extern "C" void kernel_launch(void* const* d_in, const int* in_sizes, int n_in,
                              void* d_out, int out_size, void* d_ws, size_t ws_size,
                              hipStream_t stream) {
    const float* g      = (const float*)d_in[0];
    const float* cd     = (const float*)d_in[1];
    const float* sd     = (const float*)d_in[2];
    const float* mask   = (const float*)d_in[3];
    const float* ln_w   = (const float*)d_in[4];
    const float* ln_b   = (const float*)d_in[5];
    const float* conv_w = (const float*)d_in[6];
    const float* conv_b = (const float*)d_in[7];
    const float* rpb    = (const float*)d_in[8];

    float* out  = (float*)d_out;                 // [cd_out | mask_out]
    float* qbuf = (float*)d_ws;                  // NB*NC*NHW floats
    float* kbuf = qbuf + (size_t)NB * NC * NHW;  // NB*NC*NHW floats

    qk_gemm<<<dim3(NPIX / 128), dim3(256), 0, stream>>>(
        g, cd, mask, ln_w, ln_b, conv_w, conv_b, qbuf, kbuf);
    attn_dpp<<<dim3(NB * 192), dim3(256), 0, stream>>>(
        qbuf, kbuf, cd, sd, mask, rpb, out, out + NPIX);
}